// Round 1
// baseline (240.487 us; speedup 1.0000x reference)
//
#include <hip/hip_runtime.h>

// Problem constants (B,H,T,D = 4,16,4096,64; N_TASKS=8, K_LEN=128)
#define B_   4
#define H_   16
#define T_   4096
#define D_   64
#define KL_  128
#define NT_  8
#define NTOK (B_ * T_)      // 16384 tokens
#define CAP  4096           // fixed bucket capacity (avg 2048, binomial max ~2300)

typedef __bf16 bf16;
typedef __attribute__((ext_vector_type(8))) __bf16 bf16x8;
typedef __attribute__((ext_vector_type(4))) __bf16 bf16x4;
typedef __attribute__((ext_vector_type(4))) float  floatx4;

// ws layout (ints): [0..7] per-task counts (double as cursors); [8 ..] buckets, CAP per task.
// ws bytes needed: (8 + 8*4096)*4 = 131104.

__global__ void zero_counts_k(int* __restrict__ ws) {
    if (threadIdx.x < NT_) ws[threadIdx.x] = 0;
}

// One thread per token; wave-aggregated atomics (8 atomics/wave, not 64).
__global__ void scatter_tokens_k(const int* __restrict__ trk, int* __restrict__ ws) {
    int* counts = ws;
    int* bucket = ws + NT_;
    int idx  = blockIdx.x * blockDim.x + threadIdx.x;
    int lane = threadIdx.x & 63;
    int task = (idx < NTOK) ? trk[idx] : -1;
    unsigned long long mymask = 0ull;
    int myCnt = 0;
#pragma unroll
    for (int i = 0; i < NT_; i++) {
        unsigned long long m = __ballot(task == i);
        if (task == i) mymask = m;
        if (lane == i) myCnt = (int)__popcll(m);
    }
    int b0 = 0;
    if (lane < NT_) b0 = atomicAdd(&counts[lane], myCnt);
    int myBase = __shfl(b0, (task < 0) ? 0 : task);
    if (idx < NTOK) {
        int pos = myBase + (int)__popcll(mymask & ((1ull << lane) - 1ull));
        bucket[task * CAP + pos] = idx;   // token id = b*T + t
    }
}

// Flash-style per-(task, head) attention. Block = 4 waves; each wave owns 16-token Q-tiles.
// LDS: K [128][72] bf16 (pad breaks bank conflicts), V^T [64][136] bf16, P [4 waves][16][136].
__global__ __launch_bounds__(256) void attn_k(
    const float* __restrict__ q,   const float* __restrict__ kvk,
    const float* __restrict__ kvv, const float* __restrict__ gates,
    const float* __restrict__ x,   float* __restrict__ out,
    const int* __restrict__ ws)
{
    __shared__ bf16 Kl[KL_ * 72];
    __shared__ bf16 Vt[D_ * 136];
    __shared__ bf16 Pl[4][16 * 136];

    const int task = blockIdx.z, h = blockIdx.y, chunk = blockIdx.x;
    const int cnt = ws[task];
    if (cnt == 0) return;
    const int* bucket = ws + NT_ + task * CAP;
    const float gate = gates[task];

    // ---- stage K (bf16, row-major stride 72) and V^T (stride 136) ----
    {
        const size_t kvbase = (size_t)(task * H_ + h) * (KL_ * D_ / 4);
        const float4* kf = (const float4*)kvk + kvbase;
        const float4* vf = (const float4*)kvv + kvbase;
        for (int ii = threadIdx.x; ii < KL_ * D_ / 4; ii += 256) {
            int k = ii >> 4, d4 = ii & 15;
            float4 a = kf[ii];
            bf16x4 w; w[0]=(bf16)a.x; w[1]=(bf16)a.y; w[2]=(bf16)a.z; w[3]=(bf16)a.w;
            *(bf16x4*)&Kl[k * 72 + d4 * 4] = w;
            float4 v = vf[ii];
            int d = d4 * 4;
            Vt[(d+0)*136 + k] = (bf16)v.x;
            Vt[(d+1)*136 + k] = (bf16)v.y;
            Vt[(d+2)*136 + k] = (bf16)v.z;
            Vt[(d+3)*136 + k] = (bf16)v.w;
        }
    }
    __syncthreads();

    const int wave = threadIdx.x >> 6;
    const int lane = threadIdx.x & 63;
    const int c = lane & 15, quad = lane >> 4;
    bf16* Pw = &Pl[wave][0];

    for (int ts = chunk * 4 + wave; ts * 16 < cnt; ts += 32) {
        // ---- gather Q fragments (A-layout: m=lane&15, k=quad*8+j) ----
        int slotc = ts * 16 + c;
        int tokc  = bucket[slotc < cnt ? slotc : cnt - 1];
        int bb = tokc >> 12, tt = tokc & (T_ - 1);
        const float4* qf = (const float4*)q + ((size_t)((bb * H_ + h) * T_ + tt) * (D_ / 4));
        bf16x8 aq[2];
#pragma unroll
        for (int dc = 0; dc < 2; dc++) {
            float4 f0 = qf[dc * 8 + quad * 2];
            float4 f1 = qf[dc * 8 + quad * 2 + 1];
            aq[dc][0]=(bf16)f0.x; aq[dc][1]=(bf16)f0.y; aq[dc][2]=(bf16)f0.z; aq[dc][3]=(bf16)f0.w;
            aq[dc][4]=(bf16)f1.x; aq[dc][5]=(bf16)f1.y; aq[dc][6]=(bf16)f1.z; aq[dc][7]=(bf16)f1.w;
        }
        // ---- S = Q K^T : 8 n-tiles x 2 k-chunks ----
        floatx4 sc[8];
#pragma unroll
        for (int nt = 0; nt < 8; nt++) {
            floatx4 z = {0.f, 0.f, 0.f, 0.f};
            sc[nt] = z;
#pragma unroll
            for (int dc = 0; dc < 2; dc++) {
                bf16x8 bk = *(const bf16x8*)&Kl[(nt * 16 + c) * 72 + dc * 32 + quad * 8];
                sc[nt] = __builtin_amdgcn_mfma_f32_16x16x32_bf16(aq[dc], bk, sc[nt], 0, 0, 0);
            }
        }
        // ---- softmax over 128 keys (row = quad*4+r, cols spread over nt and lane&15) ----
        float mx[4], lsum[4];
#pragma unroll
        for (int r = 0; r < 4; r++) {
            float m = -1e30f;
#pragma unroll
            for (int nt = 0; nt < 8; nt++) m = fmaxf(m, sc[nt][r]);
#pragma unroll
            for (int off = 1; off < 16; off <<= 1) m = fmaxf(m, __shfl_xor(m, off));
            mx[r] = m;
        }
#pragma unroll
        for (int r = 0; r < 4; r++) {
            float sum = 0.f;
#pragma unroll
            for (int nt = 0; nt < 8; nt++) {
                // scale 1/sqrt(64)=0.125 folded into exp2: 0.125*log2(e)
                float p = exp2f((sc[nt][r] - mx[r]) * 0.18033688011112042f);
                sc[nt][r] = p;
                sum += p;
            }
#pragma unroll
            for (int off = 1; off < 16; off <<= 1) sum += __shfl_xor(sum, off);
            lsum[r] = sum;
        }
        // ---- P: C-layout -> LDS -> A-layout (m120-verified round trip) ----
#pragma unroll
        for (int nt = 0; nt < 8; nt++)
#pragma unroll
            for (int r = 0; r < 4; r++)
                Pw[(quad * 4 + r) * 136 + nt * 16 + c] = (bf16)sc[nt][r];
        // ---- O = P V : 4 d-tiles x 4 k-chunks ----
        floatx4 acc[4];
#pragma unroll
        for (int dt = 0; dt < 4; dt++) { floatx4 z = {0.f,0.f,0.f,0.f}; acc[dt] = z; }
#pragma unroll
        for (int kc = 0; kc < 4; kc++) {
            bf16x8 ap = *(const bf16x8*)&Pw[c * 136 + kc * 32 + quad * 8];
#pragma unroll
            for (int dt = 0; dt < 4; dt++) {
                bf16x8 bv = *(const bf16x8*)&Vt[(dt * 16 + c) * 136 + kc * 32 + quad * 8];
                acc[dt] = __builtin_amdgcn_mfma_f32_16x16x32_bf16(ap, bv, acc[dt], 0, 0, 0);
            }
        }
        // ---- epilogue: normalize, gate, residual add, store ----
#pragma unroll
        for (int r = 0; r < 4; r++) {
            int slot = ts * 16 + quad * 4 + r;
            if (slot < cnt) {
                int tok = bucket[slot];
                int b2 = tok >> 12, t2 = tok & (T_ - 1);
                float scale = gate / lsum[r];
                int base = ((b2 * H_ + h) * T_ + t2) * D_;
#pragma unroll
                for (int dt = 0; dt < 4; dt++) {
                    int off = base + dt * 16 + c;
                    out[off] = x[off] + acc[dt][r] * scale;
                }
            }
        }
    }
}

extern "C" void kernel_launch(void* const* d_in, const int* in_sizes, int n_in,
                              void* d_out, int out_size, void* d_ws, size_t ws_size,
                              hipStream_t stream) {
    const float* x     = (const float*)d_in[0];
    const float* q     = (const float*)d_in[1];
    const float* kvk   = (const float*)d_in[2];
    const float* kvv   = (const float*)d_in[3];
    const float* gates = (const float*)d_in[4];
    const int*   trk   = (const int*)d_in[5];
    float* out = (float*)d_out;
    int* ws = (int*)d_ws;

    zero_counts_k<<<1, 64, 0, stream>>>(ws);
    scatter_tokens_k<<<NTOK / 256, 256, 0, stream>>>(trk, ws);
    attn_k<<<dim3(8, H_, NT_), 256, 0, stream>>>(q, kvk, kvv, gates, x, out, ws);
}